// Round 6
// baseline (267.172 us; speedup 1.0000x reference)
//
#include <hip/hip_runtime.h>
#include <hip/hip_bf16.h>
#include <math.h>

#define II 1024
#define HH 1024
#define LL 16384
#define EPSF 1e-8f
#define NBLK 256
#define XPROD 64
#define GINB 192
#define AGENT __HIP_MEMORY_SCOPE_AGENT

__device__ __forceinline__ float wred_sum(float v) {
    #pragma unroll
    for (int o = 32; o; o >>= 1) v += __shfl_down(v, o);
    return v;
}

// ---- N1: q (waves 0..1023) | gh (1024..4095) | x_emb (4096..5119) ----------
// Also zeroes the 5 sync counters used by N2 (graph-ordered predecessor reset
// -> N2's arrival counts are exact every call, any initial ws contents).
__global__ __launch_bounds__(256) void n1_kernel(
    const int* __restrict__ token, const float* __restrict__ emb,
    const float* __restrict__ hidden, const float* __restrict__ attn_w,
    const float* __restrict__ attn_b, const float* __restrict__ w_hh,
    const float* __restrict__ b_hh, const float* __restrict__ comb_w,
    const float* __restrict__ comb_b, float* __restrict__ q,
    float* __restrict__ gh, float* __restrict__ x_emb,
    unsigned* __restrict__ cnt) {
    if (blockIdx.x == 0 && threadIdx.x < 5) cnt[threadIdx.x * 16] = 0u;
    int w = (blockIdx.x * blockDim.x + threadIdx.x) >> 6;
    int lane = threadIdx.x & 63;
    const float* er = emb + (size_t)token[0] * II;
    if (w < HH) {  // q row
        const float* row = attn_w + (size_t)w * (II + HH);
        float acc = 0.f;
        for (int k = lane * 4; k < II + HH; k += 256) {
            float4 w4 = *(const float4*)(row + k);
            const float* src = (k < II) ? (er + k) : (hidden + (k - II));
            float4 x4 = *(const float4*)src;
            acc += w4.x * x4.x + w4.y * x4.y + w4.z * x4.z + w4.w * x4.w;
        }
        acc = wred_sum(acc);
        if (lane == 0) q[w] = acc + attn_b[w];
    } else if (w < 4 * HH) {  // gh row
        int r = w - HH;
        const float* row = w_hh + (size_t)r * HH;
        float acc = 0.f;
        for (int k = lane * 4; k < HH; k += 256) {
            float4 w4 = *(const float4*)(row + k);
            float4 x4 = *(const float4*)(hidden + k);
            acc += w4.x * x4.x + w4.y * x4.y + w4.z * x4.z + w4.w * x4.w;
        }
        acc = wred_sum(acc);
        if (lane == 0) gh[r] = acc + b_hh[r];
    } else {  // x_emb row
        int r = w - 4 * HH;
        const float* row = comb_w + (size_t)r * (II + HH);
        float acc = 0.f;
        #pragma unroll
        for (int k = lane * 4; k < II; k += 256) {
            float4 w4 = *(const float4*)(row + k);
            float4 x4 = *(const float4*)(er + k);
            acc += w4.x * x4.x + w4.y * x4.y + w4.z * x4.z + w4.w * x4.w;
        }
        acc = wred_sum(acc);
        if (lane == 0) x_emb[r] = acc + comb_b[r];
    }
}

// ---- N2: sims+colsum -> [pcflag] -> aa+x (blocks 0..63) -> [xcflag] ->
//          gi (blocks 64..255, w_ih warmed during wait) -> fan-in tail -------
// 256 blocks x 1024 thr = 1 block/CU (LDS ~25KB, VGPR capped by bounds) ->
// all blocks co-resident, waits cannot deadlock. Publish pattern (proven
// R4/R5): __syncthreads() drains every wave's stores, then t0 fence + add.
__global__ __launch_bounds__(1024, 4) void n2_kernel(
    const float* __restrict__ enc, const float* __restrict__ q,
    const float* __restrict__ comb_w, const float* __restrict__ x_emb,
    const float* __restrict__ w_ih, const float* __restrict__ b_ih,
    const float* __restrict__ gh, const float* __restrict__ hidden,
    const float* __restrict__ fc2_w, const float* __restrict__ fc2_b,
    const float* __restrict__ out_w, const float* __restrict__ out_b,
    float* __restrict__ e_out, float* __restrict__ part,
    float* __restrict__ psum, float* __restrict__ x, float* __restrict__ gi,
    float* __restrict__ h_new, float* __restrict__ out_scalar,
    float* __restrict__ attn_wout, unsigned* __restrict__ cnt) {
    unsigned* pc     = cnt + 0;
    unsigned* pcflag = cnt + 16;
    unsigned* xc     = cnt + 32;
    unsigned* xcflag = cnt + 48;
    unsigned* gc     = cnt + 64;

    __shared__ float s_w[64];
    __shared__ float s_tmp[4][1028];
    __shared__ float s_aa[HH];
    __shared__ float s_den;
    __shared__ float hsh[HH];
    __shared__ float f[64];
    __shared__ unsigned s_last;

    const int b = blockIdx.x, t = threadIdx.x;
    const int wv = t >> 6, lane = t & 63;

    // ---- sims + block-local colsum for enc rows [b*64, b*64+64) ----
    {
        float4 q4[4];
        #pragma unroll
        for (int j = 0; j < 4; ++j)
            q4[j] = *(const float4*)(q + lane * 4 + j * 256);
        float ss = 0.f;
        #pragma unroll
        for (int j = 0; j < 4; ++j)
            ss += q4[j].x * q4[j].x + q4[j].y * q4[j].y + q4[j].z * q4[j].z +
                  q4[j].w * q4[j].w;
        ss = wred_sum(ss);
        ss = __shfl(ss, 0);
        const float qn = fmaxf(sqrtf(ss), EPSF);

        #pragma unroll
        for (int j = 0; j < 4; ++j) {
            int r = b * 64 + wv * 4 + j;
            const float* row = enc + (size_t)r * HH;
            float dv = 0.f, sv = 0.f;
            #pragma unroll
            for (int k = 0; k < 4; ++k) {
                float4 e4 = *(const float4*)(row + lane * 4 + k * 256);
                dv += e4.x * q4[k].x + e4.y * q4[k].y + e4.z * q4[k].z +
                      e4.w * q4[k].w;
                sv += e4.x * e4.x + e4.y * e4.y + e4.z * e4.z + e4.w * e4.w;
            }
            #pragma unroll
            for (int o = 32; o; o >>= 1) {
                dv += __shfl_down(dv, o);
                sv += __shfl_down(sv, o);
            }
            if (lane == 0) {
                float en = fmaxf(sqrtf(sv), EPSF);
                // cosine in [-1,1]: fixed shift exp(s-1), no max pass needed
                float e = expf(dv / (qn * en) - 1.f);
                s_w[wv * 4 + j] = e;
                e_out[r] = e;
            }
        }
        __syncthreads();
        if (wv == 0) {
            float v = s_w[lane];
            v = wred_sum(v);
            if (lane == 0) psum[b] = v;
        }
        const float* base = enc + (size_t)b * 64 * HH;
        float acc = 0.f;
        #pragma unroll 8
        for (int r = 0; r < 64; ++r)
            acc = fmaf(s_w[r], base[(size_t)r * HH + t], acc);
        part[(size_t)b * HH + t] = acc;
    }
    __syncthreads();  // drains all waves' e/psum/part stores (vmcnt before barrier)
    if (t == 0) {
        __threadfence();
        unsigned old = __hip_atomic_fetch_add(pc, 1u, __ATOMIC_SEQ_CST, AGENT);
        if (old + 1u == NBLK)
            __hip_atomic_store(pcflag, 1u, __ATOMIC_RELEASE, AGENT);
    }

    if (b < XPROD) {
        // ---- x producers: wait for all colsum partials ----
        if (t == 0) {
            while (__hip_atomic_load(pcflag, __ATOMIC_ACQUIRE, AGENT) == 0u)
                __builtin_amdgcn_s_sleep(8);
        }
        __syncthreads();
        __threadfence();  // invalidate stale part/psum/e lines
        if (wv == 0) {
            float4 p4 = *(const float4*)(psum + lane * 4);
            float v = p4.x + p4.y + p4.z + p4.w;
            v = wred_sum(v);
            if (lane == 0) s_den = v;
        }
        {
            int cpart = t >> 8, col4 = t & 255;
            const float4* p4 = (const float4*)part;
            float4 a = {0.f, 0.f, 0.f, 0.f};
            for (int c = cpart * 64; c < cpart * 64 + 64; ++c) {
                float4 v = p4[(size_t)c * 256 + col4];
                a.x += v.x; a.y += v.y; a.z += v.z; a.w += v.w;
            }
            s_tmp[cpart][col4 * 4 + 0] = a.x;
            s_tmp[cpart][col4 * 4 + 1] = a.y;
            s_tmp[cpart][col4 * 4 + 2] = a.z;
            s_tmp[cpart][col4 * 4 + 3] = a.w;
        }
        __syncthreads();
        const float inv = 1.f / s_den;
        s_aa[t] = (s_tmp[0][t] + s_tmp[1][t] + s_tmp[2][t] + s_tmp[3][t]) * inv;
        if (t < 256) attn_wout[b * 256 + t] = e_out[b * 256 + t] * inv;
        __syncthreads();
        int r = b * 16 + wv;
        const float* row = comb_w + (size_t)r * (II + HH) + II;
        float acc = 0.f;
        #pragma unroll
        for (int k = lane * 4; k < HH; k += 256) {
            float4 w4 = *(const float4*)(row + k);
            acc += w4.x * s_aa[k] + w4.y * s_aa[k + 1] + w4.z * s_aa[k + 2] +
                   w4.w * s_aa[k + 3];
        }
        acc = wred_sum(acc);
        if (lane == 0) x[r] = fmaxf(acc + x_emb[r], 0.f);
        __syncthreads();  // drain x stores
        if (t == 0) {
            __threadfence();
            unsigned old = __hip_atomic_fetch_add(xc, 1u, __ATOMIC_SEQ_CST, AGENT);
            if (old + 1u == XPROD)
                __hip_atomic_store(xcflag, 1u, __ATOMIC_RELEASE, AGENT);
        }
        return;
    }

    // ---- gi blocks: warm w_ih row into L2 while x is being produced ----
    int r = (b - XPROD) * 16 + wv;
    const float* wrow = w_ih + (size_t)r * II;
    {
        float swarm = 0.f;
        for (int k = lane * 4; k < II; k += 256) {
            float4 v = *(const float4*)(wrow + k);
            swarm += v.x + v.y + v.z + v.w;
        }
        asm volatile("" :: "v"(swarm));  // keep the warm reads live (rule #17)
    }
    if (t == 0) {
        while (__hip_atomic_load(xcflag, __ATOMIC_ACQUIRE, AGENT) == 0u)
            __builtin_amdgcn_s_sleep(8);
    }
    __syncthreads();
    __threadfence();  // invalidate stale x lines
    {
        float acc = 0.f;
        for (int k = lane * 4; k < II; k += 256) {
            float4 w4 = *(const float4*)(wrow + k);  // L2-hot from warm pass
            float4 x4 = *(const float4*)(x + k);
            acc += w4.x * x4.x + w4.y * x4.y + w4.z * x4.z + w4.w * x4.w;
        }
        acc = wred_sum(acc);
        if (lane == 0) gi[r] = acc + b_ih[r];
    }
    __syncthreads();  // drain gi stores
    if (t == 0) {
        __threadfence();
        unsigned old = __hip_atomic_fetch_add(gc, 1u, __ATOMIC_SEQ_CST, AGENT);
        s_last = (old + 1u == GINB) ? 1u : 0u;  // true last (gc zeroed by N1)
    }
    __syncthreads();
    if (!s_last) return;
    __threadfence();  // acquire all blocks' gi stores

    // ---- tail: GRU gates + fc2/relu + out scalar ----
    float grv = gi[t] + gh[t];
    float gzv = gi[HH + t] + gh[HH + t];
    float rg = 1.f / (1.f + expf(-grv));
    float zg = 1.f / (1.f + expf(-gzv));
    float ng = tanhf(gi[2 * HH + t] + rg * gh[2 * HH + t]);
    float h = (1.f - zg) * ng + zg * hidden[t];
    hsh[t] = h;
    h_new[t] = h;
    __syncthreads();
    #pragma unroll
    for (int rr = 0; rr < 4; ++rr) {
        int r2 = wv * 4 + rr;
        const float* row = fc2_w + (size_t)r2 * HH;
        float acc = 0.f;
        #pragma unroll
        for (int k = lane * 4; k < HH; k += 256) {
            float4 w4 = *(const float4*)(row + k);
            acc += w4.x * hsh[k] + w4.y * hsh[k + 1] + w4.z * hsh[k + 2] +
                   w4.w * hsh[k + 3];
        }
        acc = wred_sum(acc);
        if (lane == 0) f[r2] = fmaxf(acc + fc2_b[r2], 0.f);
    }
    __syncthreads();
    if (t < 64) {
        float v = f[t] * out_w[t];
        v = wred_sum(v);
        if (t == 0) out_scalar[0] = v + out_b[0];
    }
}

extern "C" void kernel_launch(void* const* d_in, const int* in_sizes, int n_in,
                              void* d_out, int out_size, void* d_ws,
                              size_t ws_size, hipStream_t stream) {
    const int*   token  = (const int*)d_in[0];
    const float* hidden = (const float*)d_in[1];
    const float* enc    = (const float*)d_in[2];
    const float* emb    = (const float*)d_in[3];
    const float* attn_w = (const float*)d_in[4];
    const float* attn_b = (const float*)d_in[5];
    const float* comb_w = (const float*)d_in[6];
    const float* comb_b = (const float*)d_in[7];
    const float* w_ih   = (const float*)d_in[8];
    const float* w_hh   = (const float*)d_in[9];
    const float* b_ih   = (const float*)d_in[10];
    const float* b_hh   = (const float*)d_in[11];
    const float* fc2_w  = (const float*)d_in[12];
    const float* fc2_b  = (const float*)d_in[13];
    const float* out_w  = (const float*)d_in[14];
    const float* out_b  = (const float*)d_in[15];

    float* ws = (float*)d_ws;
    float* q     = ws;            // 1024
    float* gh    = ws + 1024;     // 3072
    float* x_emb = ws + 4096;     // 1024
    float* x     = ws + 5120;     // 1024
    float* gi    = ws + 6144;     // 3072
    float* e     = ws + 9216;     // 16384
    float* psum  = ws + 25600;    // 256
    float* part  = ws + 26624;    // 256*1024
    unsigned* cnt = (unsigned*)(ws + 26624 + 262144);  // 5 slots, 64B apart

    float* out_scalar = (float*)d_out;
    float* h_new      = (float*)d_out + 1;
    float* attn_wout  = (float*)d_out + 1 + HH;

    // N1: q + gh + x_emb (5120 waves) + counter reset
    n1_kernel<<<1280, 256, 0, stream>>>(token, emb, hidden, attn_w, attn_b,
                                        w_hh, b_hh, comb_w, comb_b, q, gh,
                                        x_emb, cnt);
    // N2: sims/colsum -> aa/x -> gi -> tail (internal flag waits)
    n2_kernel<<<NBLK, 1024, 0, stream>>>(enc, q, comb_w, x_emb, w_ih, b_ih, gh,
                                         hidden, fc2_w, fc2_b, out_w, out_b, e,
                                         part, psum, x, gi, h_new, out_scalar,
                                         attn_wout, cnt);
}

// Round 7
// 63.639 us; speedup vs baseline: 4.1983x; 4.1983x over previous
//
#include <hip/hip_runtime.h>
#include <hip/hip_bf16.h>
#include <math.h>

#define II 1024
#define HH 1024
#define LL 16384
#define EPSF 1e-8f
#define XBLK 64          // N3 blocks; each owns 16 x-rows / 16 gi-columns
#define SC_AA 4294967296.0f          // 2^32
#define ISC_AA 2.3283064365386963e-10f
#define SC_DEN 1.099511627776e12f    // 2^40
#define ISC_DEN 9.094947017729282e-13f
#define SC_GI 4294967296.0f          // 2^32
#define ISC_GI 2.3283064365386963e-10f

typedef unsigned long long ull;

__device__ __forceinline__ float wred_sum(float v) {
    #pragma unroll
    for (int o = 32; o; o >>= 1) v += __shfl_down(v, o);
    return v;
}

// ---- N1: q (waves 0..1023) | gh (1024..4095) | x_emb (4096..5119) ----------
// Block 0 additionally zeroes the int64 accumulators {aa_int[1024], den_int,
// gi_acc[3072], gc} — graph-ordered predecessor reset, exact every call.
__global__ __launch_bounds__(256) void n1_kernel(
    const int* __restrict__ token, const float* __restrict__ emb,
    const float* __restrict__ hidden, const float* __restrict__ attn_w,
    const float* __restrict__ attn_b, const float* __restrict__ w_hh,
    const float* __restrict__ b_hh, const float* __restrict__ comb_w,
    const float* __restrict__ comb_b, float* __restrict__ q,
    float* __restrict__ gh, float* __restrict__ x_emb,
    ull* __restrict__ accs) {
    if (blockIdx.x == 0) {
        for (int i = threadIdx.x; i < 1024 + 1 + 3072 + 1; i += 256)
            accs[i] = 0ull;
    }
    int w = (blockIdx.x * blockDim.x + threadIdx.x) >> 6;
    int lane = threadIdx.x & 63;
    const float* er = emb + (size_t)token[0] * II;
    if (w < HH) {  // q row
        const float* row = attn_w + (size_t)w * (II + HH);
        float acc = 0.f;
        for (int k = lane * 4; k < II + HH; k += 256) {
            float4 w4 = *(const float4*)(row + k);
            const float* src = (k < II) ? (er + k) : (hidden + (k - II));
            float4 x4 = *(const float4*)src;
            acc += w4.x * x4.x + w4.y * x4.y + w4.z * x4.z + w4.w * x4.w;
        }
        acc = wred_sum(acc);
        if (lane == 0) q[w] = acc + attn_b[w];
    } else if (w < 4 * HH) {  // gh row
        int r = w - HH;
        const float* row = w_hh + (size_t)r * HH;
        float acc = 0.f;
        for (int k = lane * 4; k < HH; k += 256) {
            float4 w4 = *(const float4*)(row + k);
            float4 x4 = *(const float4*)(hidden + k);
            acc += w4.x * x4.x + w4.y * x4.y + w4.z * x4.z + w4.w * x4.w;
        }
        acc = wred_sum(acc);
        if (lane == 0) gh[r] = acc + b_hh[r];
    } else {  // x_emb row
        int r = w - 4 * HH;
        const float* row = comb_w + (size_t)r * (II + HH);
        float acc = 0.f;
        #pragma unroll
        for (int k = lane * 4; k < II; k += 256) {
            float4 w4 = *(const float4*)(row + k);
            float4 x4 = *(const float4*)(er + k);
            acc += w4.x * x4.x + w4.y * x4.y + w4.z * x4.z + w4.w * x4.w;
        }
        acc = wred_sum(acc);
        if (lane == 0) x_emb[r] = acc + comb_b[r];
    }
}

// ---- N2: per block (64 rows): dot, row-norm, e=exp(cos-1) [fixed shift —
//      cosine in [-1,1], no max pass], then block-local colsum scattered
//      into aa_int / den_int via int64 atomics (commutative -> deterministic)
__global__ __launch_bounds__(1024) void n2_kernel(
    const float* __restrict__ enc, const float* __restrict__ q,
    float* __restrict__ e_out, ull* __restrict__ aa_int,
    ull* __restrict__ den_int) {
    __shared__ float s_w[64];
    const int b = blockIdx.x, t = threadIdx.x;
    const int wv = t >> 6, lane = t & 63;

    float4 q4[4];
    #pragma unroll
    for (int j = 0; j < 4; ++j) q4[j] = *(const float4*)(q + lane * 4 + j * 256);
    float ss = 0.f;
    #pragma unroll
    for (int j = 0; j < 4; ++j)
        ss += q4[j].x * q4[j].x + q4[j].y * q4[j].y + q4[j].z * q4[j].z +
              q4[j].w * q4[j].w;
    ss = wred_sum(ss);
    ss = __shfl(ss, 0);
    const float qn = fmaxf(sqrtf(ss), EPSF);

    #pragma unroll
    for (int j = 0; j < 4; ++j) {
        int r = b * 64 + wv * 4 + j;
        const float* row = enc + (size_t)r * HH;
        float dv = 0.f, sv = 0.f;
        #pragma unroll
        for (int k = 0; k < 4; ++k) {
            float4 e4 = *(const float4*)(row + lane * 4 + k * 256);
            dv += e4.x * q4[k].x + e4.y * q4[k].y + e4.z * q4[k].z +
                  e4.w * q4[k].w;
            sv += e4.x * e4.x + e4.y * e4.y + e4.z * e4.z + e4.w * e4.w;
        }
        #pragma unroll
        for (int o = 32; o; o >>= 1) {
            dv += __shfl_down(dv, o);
            sv += __shfl_down(sv, o);
        }
        if (lane == 0) {
            float en = fmaxf(sqrtf(sv), EPSF);
            float e = expf(dv / (qn * en) - 1.f);
            s_w[wv * 4 + j] = e;
            e_out[r] = e;
        }
    }
    __syncthreads();

    if (wv == 0) {  // partial denominator -> int64 atomic (scale 2^40)
        float v = s_w[lane];
        v = wred_sum(v);
        if (lane == 0)
            atomicAdd(den_int, (ull)(long long)llrintf(v * SC_DEN));
    }
    // block-local colsum over its 64 rows (L2-hot re-read); thread t = col t
    const float* base = enc + (size_t)b * 64 * HH;
    float acc = 0.f;
    #pragma unroll 8
    for (int r = 0; r < 64; ++r)
        acc = fmaf(s_w[r], base[(size_t)r * HH + t], acc);
    atomicAdd(&aa_int[t], (ull)(long long)llrintf(acc * SC_AA));
}

// ---- N3: 64 blocks. Each: aa from aa_int (8KB) -> 16 x-rows (own slice) ->
//      gi column-scatter (int64 atomics) -> last-arriver does GRU+fc2+out ----
__global__ __launch_bounds__(1024) void n3_kernel(
    const float* __restrict__ comb_w, const float* __restrict__ x_emb,
    const float* __restrict__ w_ih, const float* __restrict__ b_ih,
    const float* __restrict__ gh, const float* __restrict__ hidden,
    const float* __restrict__ fc2_w, const float* __restrict__ fc2_b,
    const float* __restrict__ out_w, const float* __restrict__ out_b,
    const float* __restrict__ e_in, const ull* __restrict__ aa_int,
    const ull* __restrict__ den_int, ull* __restrict__ gi_acc,
    ull* __restrict__ gc, float* __restrict__ h_new,
    float* __restrict__ out_scalar, float* __restrict__ attn_wout) {
    __shared__ float s_aa[HH];
    __shared__ float s_x[16];
    __shared__ float hsh[HH];
    __shared__ float f[64];
    __shared__ unsigned s_last;
    const int b = blockIdx.x, t = threadIdx.x;
    const int wv = t >> 6, lane = t & 63;

    const float inv_den = 1.f / ((float)((long long)den_int[0]) * ISC_DEN);
    s_aa[t] = (float)((long long)aa_int[t]) * ISC_AA * inv_den;
    if (t < 256) {  // attn weights: 64 blocks x 256 elems
        int i = b * 256 + t;
        attn_wout[i] = e_in[i] * inv_den;
    }
    __syncthreads();

    // x row r = b*16 + wv (own slice); emb-half precomputed in N1
    int r = b * 16 + wv;
    {
        const float* row = comb_w + (size_t)r * (II + HH) + II;
        float acc = 0.f;
        #pragma unroll
        for (int k = lane * 4; k < HH; k += 256) {
            float4 w4 = *(const float4*)(row + k);
            acc += w4.x * s_aa[k] + w4.y * s_aa[k + 1] + w4.z * s_aa[k + 2] +
                   w4.w * s_aa[k + 3];
        }
        acc = wred_sum(acc);
        if (lane == 0) s_x[wv] = fmaxf(acc + x_emb[r], 0.f);
    }
    __syncthreads();

    // gi column-scatter: partial_gi[rr] = sum_{k in own 16 cols} w_ih[rr,k]*x[k]
    // int64 atomics: commutative -> deterministic
    const int c0 = b * 16;
    #pragma unroll
    for (int i = 0; i < 3; ++i) {
        int rr = t + i * 1024;
        const float* wrow = w_ih + (size_t)rr * II + c0;
        float4 w0 = *(const float4*)(wrow + 0);
        float4 w1 = *(const float4*)(wrow + 4);
        float4 w2 = *(const float4*)(wrow + 8);
        float4 w3 = *(const float4*)(wrow + 12);
        float acc = w0.x * s_x[0] + w0.y * s_x[1] + w0.z * s_x[2] +
                    w0.w * s_x[3] + w1.x * s_x[4] + w1.y * s_x[5] +
                    w1.z * s_x[6] + w1.w * s_x[7] + w2.x * s_x[8] +
                    w2.y * s_x[9] + w2.z * s_x[10] + w2.w * s_x[11] +
                    w3.x * s_x[12] + w3.y * s_x[13] + w3.z * s_x[14] +
                    w3.w * s_x[15];
        atomicAdd(&gi_acc[rr], (ull)(long long)llrintf(acc * SC_GI));
    }
    __syncthreads();  // all waves' atomics issued & complete before arrival
    if (t == 0) {
        __threadfence();
        ull old = atomicAdd(gc, 1ull);
        s_last = (old + 1ull == (ull)XBLK) ? 1u : 0u;  // gc zeroed by N1
    }
    __syncthreads();
    if (!s_last) return;
    __threadfence();  // acquire all blocks' atomics

    // ---- tail: GRU gates + fc2/relu + out scalar (one block, proven R5) ----
    float gr = (float)((long long)gi_acc[t]) * ISC_GI + b_ih[t];
    float gz = (float)((long long)gi_acc[HH + t]) * ISC_GI + b_ih[HH + t];
    float gn = (float)((long long)gi_acc[2 * HH + t]) * ISC_GI + b_ih[2 * HH + t];
    float rg = 1.f / (1.f + expf(-(gr + gh[t])));
    float zg = 1.f / (1.f + expf(-(gz + gh[HH + t])));
    float ng = tanhf(gn + rg * gh[2 * HH + t]);
    float h = (1.f - zg) * ng + zg * hidden[t];
    hsh[t] = h;
    h_new[t] = h;
    __syncthreads();
    #pragma unroll
    for (int rr = 0; rr < 4; ++rr) {
        int r2 = wv * 4 + rr;
        const float* row = fc2_w + (size_t)r2 * HH;
        float acc = 0.f;
        #pragma unroll
        for (int k = lane * 4; k < HH; k += 256) {
            float4 w4 = *(const float4*)(row + k);
            acc += w4.x * hsh[k] + w4.y * hsh[k + 1] + w4.z * hsh[k + 2] +
                   w4.w * hsh[k + 3];
        }
        acc = wred_sum(acc);
        if (lane == 0) f[r2] = fmaxf(acc + fc2_b[r2], 0.f);
    }
    __syncthreads();
    if (t < 64) {
        float v = f[t] * out_w[t];
        v = wred_sum(v);
        if (t == 0) out_scalar[0] = v + out_b[0];
    }
}

extern "C" void kernel_launch(void* const* d_in, const int* in_sizes, int n_in,
                              void* d_out, int out_size, void* d_ws,
                              size_t ws_size, hipStream_t stream) {
    const int*   token  = (const int*)d_in[0];
    const float* hidden = (const float*)d_in[1];
    const float* enc    = (const float*)d_in[2];
    const float* emb    = (const float*)d_in[3];
    const float* attn_w = (const float*)d_in[4];
    const float* attn_b = (const float*)d_in[5];
    const float* comb_w = (const float*)d_in[6];
    const float* comb_b = (const float*)d_in[7];
    const float* w_ih   = (const float*)d_in[8];
    const float* w_hh   = (const float*)d_in[9];
    const float* b_ih   = (const float*)d_in[10];
    const float* b_hh   = (const float*)d_in[11];
    const float* fc2_w  = (const float*)d_in[12];
    const float* fc2_b  = (const float*)d_in[13];
    const float* out_w  = (const float*)d_in[14];
    const float* out_b  = (const float*)d_in[15];

    float* ws = (float*)d_ws;
    float* q     = ws;            // 1024
    float* gh    = ws + 1024;     // 3072
    float* x_emb = ws + 4096;     // 1024
    float* e     = ws + 5120;     // 16384
    // int64 accumulators (16B-aligned region after floats)
    ull* accs    = (ull*)(ws + 21504);
    ull* aa_int  = accs;          // 1024
    ull* den_int = accs + 1024;   // 1
    ull* gi_acc  = accs + 1025;   // 3072
    ull* gc      = accs + 4097;   // 1

    float* out_scalar = (float*)d_out;
    float* h_new      = (float*)d_out + 1;
    float* attn_wout  = (float*)d_out + 1 + HH;

    // N1: q + gh + x_emb (5120 waves) + accumulator reset
    n1_kernel<<<1280, 256, 0, stream>>>(token, emb, hidden, attn_w, attn_b,
                                        w_hh, b_hh, comb_w, comb_b, q, gh,
                                        x_emb, accs);
    // N2: sims + e_out + den/aa int64-atomic scatter
    n2_kernel<<<256, 1024, 0, stream>>>(enc, q, e, aa_int, den_int);
    // N3: aa -> x (own slice) -> gi scatter -> last-arriver tail
    n3_kernel<<<XBLK, 1024, 0, stream>>>(comb_w, x_emb, w_ih, b_ih, gh, hidden,
                                         fc2_w, fc2_b, out_w, out_b, e, aa_int,
                                         den_int, gi_acc, gc, h_new, out_scalar,
                                         attn_wout);
}

// Round 8
// 56.322 us; speedup vs baseline: 4.7436x; 1.1299x over previous
//
#include <hip/hip_runtime.h>
#include <hip/hip_bf16.h>
#include <math.h>

#define II 1024
#define HH 1024
#define LL 16384
#define EPSF 1e-8f
#define XBLK 64
#define SC_AA 4294967296.0f           // 2^32
#define ISC_AA 2.3283064365386963e-10f
#define SC_GI 4294967296.0f
#define ISC_GI 2.3283064365386963e-10f

typedef unsigned long long ull;

__device__ __forceinline__ float wred_sum(float v) {      // lane0 result
    #pragma unroll
    for (int o = 32; o; o >>= 1) v += __shfl_down(v, o);
    return v;
}
__device__ __forceinline__ float wred_sum_all(float v) {  // all lanes result
    #pragma unroll
    for (int o = 32; o; o >>= 1) v += __shfl_xor(v, o);
    return v;
}

// ---- N1: q = attn_w.[emb|h0]+attn_b (1024 waves) + zero int64 accumulators -
// accs layout: aa_int[4][1024] | gi_acc[2][3072] | gc  -> 10241 ulls
__global__ __launch_bounds__(256) void n1_kernel(
    const int* __restrict__ token, const float* __restrict__ emb,
    const float* __restrict__ hidden, const float* __restrict__ attn_w,
    const float* __restrict__ attn_b, float* __restrict__ q,
    ull* __restrict__ accs) {
    for (int i = blockIdx.x * 256 + threadIdx.x; i < 10241; i += 65536)
        accs[i] = 0ull;
    int w = (blockIdx.x * blockDim.x + threadIdx.x) >> 6;  // 0..1023
    int lane = threadIdx.x & 63;
    const float* er = emb + (size_t)token[0] * II;
    const float* row = attn_w + (size_t)w * (II + HH);
    float acc = 0.f;
    for (int k = lane * 4; k < II + HH; k += 256) {
        float4 w4 = *(const float4*)(row + k);
        const float* src = (k < II) ? (er + k) : (hidden + (k - II));
        float4 x4 = *(const float4*)src;
        acc += w4.x * x4.x + w4.y * x4.y + w4.z * x4.z + w4.w * x4.w;
    }
    acc = wred_sum(acc);
    if (lane == 0) q[w] = acc + attn_b[w];
}

// ---- N2: single enc pass: sims + register-level colsum fusion; then
//      gh rows (waves 0..11) + x_emb rows (waves 12..15) in the same node ----
__global__ __launch_bounds__(1024) void n2_kernel(
    const int* __restrict__ token, const float* __restrict__ emb,
    const float* __restrict__ enc, const float* __restrict__ q,
    const float* __restrict__ hidden, const float* __restrict__ w_hh,
    const float* __restrict__ b_hh, const float* __restrict__ comb_w,
    const float* __restrict__ comb_b, float* __restrict__ e_out,
    float* __restrict__ psum, float* __restrict__ gh,
    float* __restrict__ x_emb, ull* __restrict__ aa_int) {
    __shared__ float s_colw[16][1024];  // per-wave column partials (64 KB)
    __shared__ float s_red[16];
    const int b = blockIdx.x, t = threadIdx.x;
    const int wv = t >> 6, lane = t & 63;

    // q fragment + qn (butterfly -> all lanes)
    float4 q4[4];
    #pragma unroll
    for (int j = 0; j < 4; ++j) q4[j] = *(const float4*)(q + lane * 4 + j * 256);
    float ss = 0.f;
    #pragma unroll
    for (int j = 0; j < 4; ++j)
        ss += q4[j].x * q4[j].x + q4[j].y * q4[j].y + q4[j].z * q4[j].z +
              q4[j].w * q4[j].w;
    ss = wred_sum_all(ss);
    const float qn = fmaxf(sqrtf(ss), EPSF);

    // 4 rows/wave: dot + norm -> e (all lanes), colsum folded in registers.
    // cosine in [-1,1]: fixed shift exp(s-1) replaces the softmax max pass.
    float cs[16];
    #pragma unroll
    for (int i = 0; i < 16; ++i) cs[i] = 0.f;
    float ewave = 0.f;
    #pragma unroll
    for (int j = 0; j < 4; ++j) {
        int r = b * 64 + wv * 4 + j;
        const float* row = enc + (size_t)r * HH;
        float4 e4[4];
        float dv = 0.f, sv = 0.f;
        #pragma unroll
        for (int k = 0; k < 4; ++k) {
            e4[k] = *(const float4*)(row + lane * 4 + k * 256);
            dv += e4[k].x * q4[k].x + e4[k].y * q4[k].y + e4[k].z * q4[k].z +
                  e4[k].w * q4[k].w;
            sv += e4[k].x * e4[k].x + e4[k].y * e4[k].y + e4[k].z * e4[k].z +
                  e4[k].w * e4[k].w;
        }
        dv = wred_sum_all(dv);
        sv = wred_sum_all(sv);
        float en = fmaxf(sqrtf(sv), EPSF);
        float e = expf(dv / (qn * en) - 1.f);
        if (lane == 0) e_out[r] = e;
        ewave += e;
        #pragma unroll
        for (int k = 0; k < 4; ++k) {
            cs[k * 4 + 0] = fmaf(e, e4[k].x, cs[k * 4 + 0]);
            cs[k * 4 + 1] = fmaf(e, e4[k].y, cs[k * 4 + 1]);
            cs[k * 4 + 2] = fmaf(e, e4[k].z, cs[k * 4 + 2]);
            cs[k * 4 + 3] = fmaf(e, e4[k].w, cs[k * 4 + 3]);
        }
    }
    // stage per-wave colsums, tree-reduce, one atomic per column
    #pragma unroll
    for (int k = 0; k < 4; ++k)
        *(float4*)&s_colw[wv][k * 256 + lane * 4] = *(float4*)&cs[k * 4];
    if (lane == 0) s_red[wv] = ewave;
    __syncthreads();
    if (wv == 0) {  // psum[b]: plain store (no single-cell atomic)
        float v = (lane < 16) ? s_red[lane] : 0.f;
        v = wred_sum(v);
        if (lane == 0) psum[b] = v;
    }
    {
        float a = 0.f;
        #pragma unroll
        for (int w = 0; w < 16; ++w) a += s_colw[w][t];
        atomicAdd(&aa_int[(b & 3) * 1024 + t],
                  (ull)(long long)llrintf(a * SC_AA));
    }

    // gh rows (waves 0..11) / x_emb rows (waves 12..15)
    if (wv < 12) {
        int r = b * 12 + wv;
        const float* row = w_hh + (size_t)r * HH;
        float acc = 0.f;
        #pragma unroll
        for (int k = lane * 4; k < HH; k += 256) {
            float4 w4 = *(const float4*)(row + k);
            float4 x4 = *(const float4*)(hidden + k);
            acc += w4.x * x4.x + w4.y * x4.y + w4.z * x4.z + w4.w * x4.w;
        }
        acc = wred_sum(acc);
        if (lane == 0) gh[r] = acc + b_hh[r];
    } else {
        int r = b * 4 + (wv - 12);
        const float* row = comb_w + (size_t)r * (II + HH);
        const float* er = emb + (size_t)token[0] * II;
        float acc = 0.f;
        #pragma unroll
        for (int k = lane * 4; k < II; k += 256) {
            float4 w4 = *(const float4*)(row + k);
            float4 x4 = *(const float4*)(er + k);
            acc += w4.x * x4.x + w4.y * x4.y + w4.z * x4.z + w4.w * x4.w;
        }
        acc = wred_sum(acc);
        if (lane == 0) x_emb[r] = acc + comb_b[r];
    }
}

// ---- N3: 64 blocks: aa -> attn_wout -> fc2 warm -> x (own 16 rows) ->
//      gi column-scatter (2 replicas) -> last-arriver tail (GRU+fc2+out) -----
__global__ __launch_bounds__(1024) void n3_kernel(
    const float* __restrict__ comb_w, const float* __restrict__ x_emb,
    const float* __restrict__ w_ih, const float* __restrict__ b_ih,
    const float* __restrict__ gh, const float* __restrict__ hidden,
    const float* __restrict__ fc2_w, const float* __restrict__ fc2_b,
    const float* __restrict__ out_w, const float* __restrict__ out_b,
    const float* __restrict__ e_in, const float* __restrict__ psum,
    const ull* __restrict__ aa_int, ull* __restrict__ gi_acc,
    ull* __restrict__ gc, float* __restrict__ h_new,
    float* __restrict__ out_scalar, float* __restrict__ attn_wout) {
    __shared__ float s_aa[HH];
    __shared__ float s_x[16];
    __shared__ float hsh[HH];
    __shared__ float f[64];
    __shared__ unsigned s_last;
    const int b = blockIdx.x, t = threadIdx.x;
    const int wv = t >> 6, lane = t & 63;

    // den: every wave computes redundantly (4 KB L2), no sync needed
    float4 p4 = *(const float4*)(psum + lane * 4);
    float den = wred_sum_all(p4.x + p4.y + p4.z + p4.w);
    const float inv_den = 1.f / den;

    s_aa[t] = (float)((long long)(aa_int[t] + aa_int[1024 + t] +
                                  aa_int[2048 + t] + aa_int[3072 + t])) *
              ISC_AA * inv_den;
    if (t < 256) {
        int i = b * 256 + t;
        attn_wout[i] = e_in[i] * inv_den;
    }
    // warm fc2_w into this XCD's L2 (tail reads it L2-hot)
    {
        float sw = 0.f;
        #pragma unroll
        for (int i = 0; i < 16; ++i) {
            float4 v = *(const float4*)(fc2_w + t * 4 + i * 4096);
            sw += v.x + v.y + v.z + v.w;
        }
        asm volatile("" :: "v"(sw));
    }
    __syncthreads();

    // x row r = b*16 + wv (own slice)
    int r = b * 16 + wv;
    {
        const float* row = comb_w + (size_t)r * (II + HH) + II;
        float acc = 0.f;
        #pragma unroll
        for (int k = lane * 4; k < HH; k += 256) {
            float4 w4 = *(const float4*)(row + k);
            acc += w4.x * s_aa[k] + w4.y * s_aa[k + 1] + w4.z * s_aa[k + 2] +
                   w4.w * s_aa[k + 3];
        }
        acc = wred_sum(acc);
        if (lane == 0) s_x[wv] = fmaxf(acc + x_emb[r], 0.f);
    }
    __syncthreads();

    // gi column-scatter: own 16 cols of w_ih; 2 replicas (32-deep contention)
    const int c0 = b * 16;
    ull* grep = gi_acc + (size_t)(b & 1) * 3072;
    #pragma unroll
    for (int i = 0; i < 3; ++i) {
        int rr = t + i * 1024;
        const float* wrow = w_ih + (size_t)rr * II + c0;
        float4 w0 = *(const float4*)(wrow + 0);
        float4 w1 = *(const float4*)(wrow + 4);
        float4 w2 = *(const float4*)(wrow + 8);
        float4 w3 = *(const float4*)(wrow + 12);
        float acc = w0.x * s_x[0] + w0.y * s_x[1] + w0.z * s_x[2] +
                    w0.w * s_x[3] + w1.x * s_x[4] + w1.y * s_x[5] +
                    w1.z * s_x[6] + w1.w * s_x[7] + w2.x * s_x[8] +
                    w2.y * s_x[9] + w2.z * s_x[10] + w2.w * s_x[11] +
                    w3.x * s_x[12] + w3.y * s_x[13] + w3.z * s_x[14] +
                    w3.w * s_x[15];
        atomicAdd(&grep[rr], (ull)(long long)llrintf(acc * SC_GI));
    }
    __syncthreads();  // all waves' atomics complete before arrival
    if (t == 0) {
        __threadfence();
        ull old = atomicAdd(gc, 1ull);
        s_last = (old + 1ull == (ull)XBLK) ? 1u : 0u;  // gc zeroed by N1
    }
    __syncthreads();
    if (!s_last) return;
    __threadfence();  // acquire all blocks' atomics

    // ---- tail: GRU gates + fc2/relu + out scalar ----
    float gr = (float)((long long)(gi_acc[t] + gi_acc[3072 + t])) * ISC_GI +
               b_ih[t];
    float gz = (float)((long long)(gi_acc[HH + t] + gi_acc[3072 + HH + t])) *
                   ISC_GI + b_ih[HH + t];
    float gn = (float)((long long)(gi_acc[2 * HH + t] +
                                   gi_acc[3072 + 2 * HH + t])) * ISC_GI +
               b_ih[2 * HH + t];
    float rg = 1.f / (1.f + expf(-(gr + gh[t])));
    float zg = 1.f / (1.f + expf(-(gz + gh[HH + t])));
    float ng = tanhf(gn + rg * gh[2 * HH + t]);
    float h = (1.f - zg) * ng + zg * hidden[t];
    hsh[t] = h;
    h_new[t] = h;
    __syncthreads();
    #pragma unroll
    for (int rr2 = 0; rr2 < 4; ++rr2) {
        int r2 = wv * 4 + rr2;
        const float* row = fc2_w + (size_t)r2 * HH;
        float acc = 0.f;
        #pragma unroll
        for (int k = lane * 4; k < HH; k += 256) {
            float4 w4 = *(const float4*)(row + k);
            acc += w4.x * hsh[k] + w4.y * hsh[k + 1] + w4.z * hsh[k + 2] +
                   w4.w * hsh[k + 3];
        }
        acc = wred_sum(acc);
        if (lane == 0) f[r2] = fmaxf(acc + fc2_b[r2], 0.f);
    }
    __syncthreads();
    if (t < 64) {
        float v = f[t] * out_w[t];
        v = wred_sum(v);
        if (t == 0) out_scalar[0] = v + out_b[0];
    }
}

extern "C" void kernel_launch(void* const* d_in, const int* in_sizes, int n_in,
                              void* d_out, int out_size, void* d_ws,
                              size_t ws_size, hipStream_t stream) {
    const int*   token  = (const int*)d_in[0];
    const float* hidden = (const float*)d_in[1];
    const float* enc    = (const float*)d_in[2];
    const float* emb    = (const float*)d_in[3];
    const float* attn_w = (const float*)d_in[4];
    const float* attn_b = (const float*)d_in[5];
    const float* comb_w = (const float*)d_in[6];
    const float* comb_b = (const float*)d_in[7];
    const float* w_ih   = (const float*)d_in[8];
    const float* w_hh   = (const float*)d_in[9];
    const float* b_ih   = (const float*)d_in[10];
    const float* b_hh   = (const float*)d_in[11];
    const float* fc2_w  = (const float*)d_in[12];
    const float* fc2_b  = (const float*)d_in[13];
    const float* out_w  = (const float*)d_in[14];
    const float* out_b  = (const float*)d_in[15];

    float* ws = (float*)d_ws;
    float* q     = ws;            // 1024
    float* gh    = ws + 1024;     // 3072
    float* x_emb = ws + 4096;     // 1024
    float* e     = ws + 5120;     // 16384
    float* psum  = ws + 21504;    // 256
    ull* accs    = (ull*)(ws + 21760);
    ull* aa_int  = accs;          // 4*1024
    ull* gi_acc  = accs + 4096;   // 2*3072
    ull* gc      = accs + 10240;  // 1

    float* out_scalar = (float*)d_out;
    float* h_new      = (float*)d_out + 1;
    float* attn_wout  = (float*)d_out + 1 + HH;

    // N1: q + accumulator reset
    n1_kernel<<<256, 256, 0, stream>>>(token, emb, hidden, attn_w, attn_b, q,
                                       accs);
    // N2: single-pass sims+colsum (+gh, x_emb in the shadow)
    n2_kernel<<<256, 1024, 0, stream>>>(token, emb, enc, q, hidden, w_hh, b_hh,
                                        comb_w, comb_b, e, psum, gh, x_emb,
                                        aa_int);
    // N3: aa -> x -> gi scatter -> last-arriver tail
    n3_kernel<<<XBLK, 1024, 0, stream>>>(comb_w, x_emb, w_ih, b_ih, gh, hidden,
                                         fc2_w, fc2_b, out_w, out_b, e, psum,
                                         aa_int, gi_acc, gc, h_new, out_scalar,
                                         attn_wout);
}